// Round 11
// baseline (214.915 us; speedup 1.0000x reference)
//
#include <hip/hip_runtime.h>
#include <hip/hip_bf16.h>
#include <cstdint>

#define N_SPK 1024
#define M_UTT 20
#define D_DIM 768
#define NM_ROWS (N_SPK * M_UTT)   // 20480 utterances / rows

static constexpr float EPS = 1e-8f;

typedef __attribute__((ext_vector_type(8))) short short8;   // 8 x bf16 (4 VGPRs)
typedef __attribute__((ext_vector_type(4))) float floatx4;  // MFMA accumulator

__device__ __forceinline__ unsigned short bf16bits(float x) {
    __hip_bfloat16 h = __float2bfloat16(x);
    return *(unsigned short*)&h;
}

__device__ __forceinline__ float wave_sum(float v) {
    #pragma unroll
    for (int o = 32; o > 0; o >>= 1) v += __shfl_xor(v, o);
    return v;
}

// ---------------------------------------------------------------------------
// Kernel 1 (prep): per speaker, read emb once (float2/thread, 384 thr),
// centroid + 20 utterance norms, bf16 Chat/Ehat ([m][i][d]) ushort2 stores.
// Zero-inits ctr/accum. Unchanged from R7.
// ---------------------------------------------------------------------------
__global__ __launch_bounds__(384) void prep_kernel(const float* __restrict__ emb,
                                                   __hip_bfloat16* __restrict__ ehat,
                                                   __hip_bfloat16* __restrict__ chat,
                                                   int* __restrict__ ctr,
                                                   float* __restrict__ accum) {
    const int i = blockIdx.x;      // speaker
    const int t = threadIdx.x;     // 0..383
    const int wave = t >> 6, lane = t & 63;

    if (i == 0 && t == 0) { *ctr = 0; *accum = 0.f; }

    const float2* src = (const float2*)(emb + (size_t)i * M_UTT * D_DIM);

    float2 v[M_UTT];
    float ss[M_UTT];
    float2 cen = {0.f, 0.f};
    #pragma unroll
    for (int m = 0; m < M_UTT; ++m) {
        const float2 x = src[m * 384 + t];
        v[m] = x;
        ss[m] = x.x * x.x + x.y * x.y;
        cen.x += x.x; cen.y += x.y;
    }
    cen.x *= (1.f / M_UTT); cen.y *= (1.f / M_UTT);
    float css = cen.x * cen.x + cen.y * cen.y;

    __shared__ float red[M_UTT + 1][6];
    #pragma unroll
    for (int m = 0; m < M_UTT; ++m) {
        const float s = wave_sum(ss[m]);
        if (lane == 0) red[m][wave] = s;
    }
    {
        const float s = wave_sum(css);
        if (lane == 0) red[M_UTT][wave] = s;
    }
    __syncthreads();

    #pragma unroll
    for (int m = 0; m < M_UTT; ++m) {
        const float tot = red[m][0] + red[m][1] + red[m][2] +
                          red[m][3] + red[m][4] + red[m][5];
        const float rn = 1.0f / fmaxf(sqrtf(tot), EPS);
        ushort2 o;
        o.x = bf16bits(v[m].x * rn); o.y = bf16bits(v[m].y * rn);
        *(ushort2*)((unsigned short*)ehat + ((size_t)(m * N_SPK + i)) * D_DIM + 2 * t) = o;
    }
    {
        const float tot = red[M_UTT][0] + red[M_UTT][1] + red[M_UTT][2] +
                          red[M_UTT][3] + red[M_UTT][4] + red[M_UTT][5];
        const float rn = 1.0f / fmaxf(sqrtf(tot), EPS);
        ushort2 o;
        o.x = bf16bits(cen.x * rn); o.y = bf16bits(cen.y * rn);
        *(ushort2*)((unsigned short*)chat + (size_t)i * D_DIM + 2 * t) = o;
    }
}

// ---------------------------------------------------------------------------
// Kernel 2: direct-to-register single-wave GEMM — NO LDS, NO barriers.
// One wave per block, 64x64 tile. The MFMA A/B fragment layout
// (row = it*16+c, k-octet = quad) is loaded STRAIGHT from global: lane(c,quad)
// reads 16B at row*768 + quad*8 + k0. Each c-group's 4 quads cover one full
// 64B line (bytes fetched == bytes used). All 24 k-offsets fit the 13-bit
// immediate (<=1472B), so the unrolled loop is pure {8 loads + 16 MFMA} with
// zero address VALU; the compiler pipelines plain VGPR loads with its own
// fine-grained vmcnt (the thing it refuses to do for global_load_lds).
// Block order: bu fastest within XCD -> co-resident waves share bj, so B
// k-slices (4KB/iter) stay L1-hot; per-XCD A slab (3.9MB) stays L2-resident.
// ---------------------------------------------------------------------------
__global__ __launch_bounds__(64) void gemm_fused_kernel(
        const __hip_bfloat16* __restrict__ ehat,
        const __hip_bfloat16* __restrict__ chat,
        const float* __restrict__ wp,
        float* __restrict__ Psum,
        float* __restrict__ T) {
    const int lane = threadIdx.x;   // 0..63
    const int c = lane & 15;
    const int quad = lane >> 4;

    const int xcd = blockIdx.x & 7;
    const int idx = blockIdx.x >> 3;        // 0..639
    const int bu  = xcd * 40 + (idx % 40);  // 0..319  (bu fastest)
    const int bj  = idx / 40;               // 0..15
    const int m   = bu >> 4;                // 16 bu-tiles per m
    const int rb  = bu & 15;
    const int u0  = bu * 64;
    const int j0  = bj * 64;

    // 8 loop-invariant base addresses; k-loop uses immediate offsets only
    const short* Abase[4];
    const short* Bbase[4];
    #pragma unroll
    for (int it = 0; it < 4; ++it)
        Abase[it] = (const short*)ehat + (size_t)(u0 + it * 16 + c) * D_DIM + quad * 8;
    #pragma unroll
    for (int jt = 0; jt < 4; ++jt)
        Bbase[jt] = (const short*)chat + (size_t)(j0 + jt * 16 + c) * D_DIM + quad * 8;

    floatx4 acc[4][4] = {};

    #pragma unroll
    for (int k0 = 0; k0 < D_DIM; k0 += 32) {
        short8 af[4], bf[4];
        #pragma unroll
        for (int it = 0; it < 4; ++it) af[it] = *(const short8*)(Abase[it] + k0);
        #pragma unroll
        for (int jt = 0; jt < 4; ++jt) bf[jt] = *(const short8*)(Bbase[jt] + k0);

        #pragma unroll
        for (int it = 0; it < 4; ++it)
            #pragma unroll
            for (int jt = 0; jt < 4; ++jt)
                acc[it][jt] = __builtin_amdgcn_mfma_f32_16x16x32_bf16(af[it], bf[jt], acc[it][jt], 0, 0, 0);
    }

    const float w = wp[0];

    // per-column fixed-offset partial: sum exp(w*(cos-1)) over the 64 rows
    #pragma unroll
    for (int jt = 0; jt < 4; ++jt) {
        float sm = 0.f;
        #pragma unroll
        for (int it = 0; it < 4; ++it)
            #pragma unroll
            for (int r = 0; r < 4; ++r)
                sm += __expf(w * (acc[it][jt][r] - 1.0f));
        sm += __shfl_xor(sm, 16);
        sm += __shfl_xor(sm, 32);
        if (quad == 0) Psum[(size_t)bu * N_SPK + j0 + jt * 16 + c] = sm;
    }

    // target sims: row within m-slab == (m*1024+col)/20 (unique owner -> store)
    #pragma unroll
    for (int it = 0; it < 4; ++it) {
        #pragma unroll
        for (int jt = 0; jt < 4; ++jt) {
            const int col = j0 + jt * 16 + c;
            const int g = m * N_SPK + col;
            const int istar = g / M_UTT;
            const int rloc = rb * 64 + it * 16 + quad * 4;   // row within m-slab
            #pragma unroll
            for (int r = 0; r < 4; ++r) {
                if (rloc + r == istar) T[g] = acc[it][jt][r];
            }
        }
    }
}

// ---------------------------------------------------------------------------
// Kernel 3: combine 16 row-block partials per (m,j) -> loss term; block sum;
// last-block writes output (ctr/accum zeroed by prep).
// term = (w*T+b) - ((w+b) + log S) = w*(T-1) - log S.
// ---------------------------------------------------------------------------
__global__ void combine_kernel(const float* __restrict__ Psum,
                               const float* __restrict__ T,
                               const float* __restrict__ wp,
                               int* __restrict__ ctr,
                               float* __restrict__ accum,
                               float* __restrict__ out) {
    const int p = blockIdx.x * 256 + threadIdx.x;
    const int m = p >> 10;
    const int j = p & 1023;
    const float w = wp[0];

    float S = 0.f;
    #pragma unroll
    for (int rb = 0; rb < 16; ++rb)
        S += Psum[(size_t)(m * 16 + rb) * N_SPK + j];
    const float term = w * (T[p] - 1.0f) - __logf(S);

    __shared__ float red[256];
    red[threadIdx.x] = term;
    __syncthreads();
    for (int o = 128; o > 0; o >>= 1) {
        if (threadIdx.x < o) red[threadIdx.x] += red[threadIdx.x + o];
        __syncthreads();
    }
    if (threadIdx.x == 0) {
        atomicAdd(accum, red[0]);
        __threadfence();
        const int old = atomicAdd(ctr, 1);
        if (old == 79) {
            const float a = atomicAdd(accum, 0.0f);   // coherent read
            out[0] = -a / (float)NM_ROWS;
        }
    }
}

// ---------------------------------------------------------------------------
extern "C" void kernel_launch(void* const* d_in, const int* in_sizes, int n_in,
                              void* d_out, int out_size, void* d_ws, size_t ws_size,
                              hipStream_t stream) {
    const float* emb = (const float*)d_in[0];
    const float* wp  = (const float*)d_in[1];
    float* out = (float*)d_out;

    char* ws = (char*)d_ws;
    //   Ehat bf16 [M][N][D] : 31,457,280  @ 0
    //   Chat bf16 [N][D]    :  1,572,864  @ 31,457,280
    //   Psum f32 [320][N]   :  1,310,720  @ 33,030,144
    //   T    f32 [M][N]     :     81,920  @ 34,340,864
    //   ctr  i32 + accum f32:          8  @ 34,422,784
    __hip_bfloat16* ehat = (__hip_bfloat16*)(ws);
    __hip_bfloat16* chat = (__hip_bfloat16*)(ws + 31457280);
    float* Psum  = (float*)(ws + 33030144);
    float* T     = (float*)(ws + 34340864);
    int*   ctr   = (int*)  (ws + 34422784);
    float* accum = (float*)(ws + 34422788);

    prep_kernel<<<dim3(N_SPK), dim3(384), 0, stream>>>(emb, ehat, chat, ctr, accum);
    gemm_fused_kernel<<<dim3(5120), dim3(64), 0, stream>>>(ehat, chat, wp, Psum, T);
    combine_kernel<<<dim3(80), dim3(256), 0, stream>>>(Psum, T, wp, ctr, accum, out);
}

// Round 12
// 170.765 us; speedup vs baseline: 1.2585x; 1.2585x over previous
//
#include <hip/hip_runtime.h>
#include <hip/hip_bf16.h>
#include <cstdint>

#define N_SPK 1024
#define M_UTT 20
#define D_DIM 768
#define NM_ROWS (N_SPK * M_UTT)   // 20480 utterances / rows

static constexpr float EPS = 1e-8f;

typedef __attribute__((ext_vector_type(8))) short short8;   // 8 x bf16 (4 VGPRs)
typedef __attribute__((ext_vector_type(4))) float floatx4;  // MFMA accumulator

__device__ __forceinline__ void load16_to_lds(const void* g, void* l) {
    __builtin_amdgcn_global_load_lds(
        (const __attribute__((address_space(1))) uint32_t*)g,
        (__attribute__((address_space(3))) uint32_t*)l, 16, 0, 0);
}

__device__ __forceinline__ unsigned short bf16bits(float x) {
    __hip_bfloat16 h = __float2bfloat16(x);
    return *(unsigned short*)&h;
}

__device__ __forceinline__ float wave_sum(float v) {
    #pragma unroll
    for (int o = 32; o > 0; o >>= 1) v += __shfl_xor(v, o);
    return v;
}

// ---------------------------------------------------------------------------
// Kernel 1 (prep): per speaker, read emb once (float2/thread, 384 thr),
// centroid + 20 utterance norms, bf16 Chat/Ehat ([m][i][d]) ushort2 stores.
// Zero-inits ctr/accum. Unchanged from R7 (BW-bound; R3-vs-R4 accounting
// shows float4/float2 variants are equal).
// ---------------------------------------------------------------------------
__global__ __launch_bounds__(384) void prep_kernel(const float* __restrict__ emb,
                                                   __hip_bfloat16* __restrict__ ehat,
                                                   __hip_bfloat16* __restrict__ chat,
                                                   int* __restrict__ ctr,
                                                   float* __restrict__ accum) {
    const int i = blockIdx.x;      // speaker
    const int t = threadIdx.x;     // 0..383
    const int wave = t >> 6, lane = t & 63;

    if (i == 0 && t == 0) { *ctr = 0; *accum = 0.f; }

    const float2* src = (const float2*)(emb + (size_t)i * M_UTT * D_DIM);

    float2 v[M_UTT];
    float ss[M_UTT];
    float2 cen = {0.f, 0.f};
    #pragma unroll
    for (int m = 0; m < M_UTT; ++m) {
        const float2 x = src[m * 384 + t];
        v[m] = x;
        ss[m] = x.x * x.x + x.y * x.y;
        cen.x += x.x; cen.y += x.y;
    }
    cen.x *= (1.f / M_UTT); cen.y *= (1.f / M_UTT);
    float css = cen.x * cen.x + cen.y * cen.y;

    __shared__ float red[M_UTT + 1][6];
    #pragma unroll
    for (int m = 0; m < M_UTT; ++m) {
        const float s = wave_sum(ss[m]);
        if (lane == 0) red[m][wave] = s;
    }
    {
        const float s = wave_sum(css);
        if (lane == 0) red[M_UTT][wave] = s;
    }
    __syncthreads();

    #pragma unroll
    for (int m = 0; m < M_UTT; ++m) {
        const float tot = red[m][0] + red[m][1] + red[m][2] +
                          red[m][3] + red[m][4] + red[m][5];
        const float rn = 1.0f / fmaxf(sqrtf(tot), EPS);
        ushort2 o;
        o.x = bf16bits(v[m].x * rn); o.y = bf16bits(v[m].y * rn);
        *(ushort2*)((unsigned short*)ehat + ((size_t)(m * N_SPK + i)) * D_DIM + 2 * t) = o;
    }
    {
        const float tot = red[M_UTT][0] + red[M_UTT][1] + red[M_UTT][2] +
                          red[M_UTT][3] + red[M_UTT][4] + red[M_UTT][5];
        const float rn = 1.0f / fmaxf(sqrtf(tot), EPS);
        ushort2 o;
        o.x = bf16bits(cen.x * rn); o.y = bf16bits(cen.y * rn);
        *(ushort2*)((unsigned short*)chat + (size_t)i * D_DIM + 2 * t) = o;
    }
}

// ---------------------------------------------------------------------------
// Kernel 2: GEMM + fixed-offset softmax partial epilogue.
// R12: 64x64 tile, 2 waves (32 rows each), 2x4 MFMA acc per wave (32 acc
// VGPRs), BK=32 single-buffered — same proven K-loop discipline as R7 but
// ~95 total VGPRs -> 5 waves/SIMD -> 10 co-resident blocks/CU (vs 6),
// grid 5120 = 20/CU = two clean occupancy rounds. TLP attack on the
// stage->drain latency.
// XCD swizzle (bj fastest, per-XCD A slab 3.9MB + B resident) + XOR LDS
// swizzle (0 conflicts measured) retained.
// ---------------------------------------------------------------------------
__global__ __launch_bounds__(128) void gemm_fused_kernel(
        const __hip_bfloat16* __restrict__ ehat,
        const __hip_bfloat16* __restrict__ chat,
        const float* __restrict__ wp,
        float* __restrict__ Psum,
        float* __restrict__ T) {
    __shared__ __hip_bfloat16 As[64 * 32];   // 4 KB
    __shared__ __hip_bfloat16 Bs[64 * 32];   // 4 KB
    __shared__ float red[2][64];

    const int t = threadIdx.x;          // 0..127
    const int lane = t & 63;
    const int wid = t >> 6;             // wave: row half (32 rows each)
    const int c = lane & 15;
    const int quad = lane >> 4;

    const int xcd = blockIdx.x & 7;
    const int idx = blockIdx.x >> 3;        // 0..639
    const int bu  = xcd * 40 + (idx >> 4);  // 0..319 (64-row tiles)
    const int bj  = idx & 15;               // 0..15  (bj fastest within XCD)
    const int m   = bu >> 4;                // 16 bu-tiles per m
    const int rb  = bu & 15;
    const int u0  = bu * 64;
    const int j0  = bj * 64;

    const short* Ag = (const short*)ehat + (size_t)u0 * D_DIM;
    const short* Bg = (const short*)chat + (size_t)j0 * D_DIM;

    floatx4 acc[2][4] = {};

    for (int k0 = 0; k0 < D_DIM; k0 += 32) {
        // stage A + B: 256 16B chunks each; thread t covers ci = s*128+t
        #pragma unroll
        for (int s = 0; s < 2; ++s) {
            const int ci  = s * 128 + t;
            const int row = ci >> 2;
            const int q   = (ci & 3) ^ ((row >> 1) & 3);
            load16_to_lds(Ag + (size_t)row * D_DIM + k0 + q * 8, (short*)As + ci * 8);
            load16_to_lds(Bg + (size_t)row * D_DIM + k0 + q * 8, (short*)Bs + ci * 8);
        }
        __syncthreads();

        short8 af[2], bf[4];
        #pragma unroll
        for (int it = 0; it < 2; ++it) {
            const int r = wid * 32 + it * 16 + c;
            const int slot = r * 4 + (quad ^ ((r >> 1) & 3));
            af[it] = *(const short8*)((const short*)As + slot * 8);
        }
        #pragma unroll
        for (int jt = 0; jt < 4; ++jt) {
            const int r = jt * 16 + c;
            const int slot = r * 4 + (quad ^ ((r >> 1) & 3));
            bf[jt] = *(const short8*)((const short*)Bs + slot * 8);
        }

        #pragma unroll
        for (int it = 0; it < 2; ++it)
            #pragma unroll
            for (int jt = 0; jt < 4; ++jt)
                acc[it][jt] = __builtin_amdgcn_mfma_f32_16x16x32_bf16(af[it], bf[jt], acc[it][jt], 0, 0, 0);
        __syncthreads();
    }

    const float w = wp[0];

    // per-column fixed-offset partial over the wave's 32 rows
    #pragma unroll
    for (int jt = 0; jt < 4; ++jt) {
        float sm = 0.f;
        #pragma unroll
        for (int it = 0; it < 2; ++it)
            #pragma unroll
            for (int r = 0; r < 4; ++r)
                sm += __expf(w * (acc[it][jt][r] - 1.0f));
        sm += __shfl_xor(sm, 16);
        sm += __shfl_xor(sm, 32);
        if (quad == 0) red[wid][jt * 16 + c] = sm;
    }

    // target sims: row within m-slab == (m*1024+col)/20 (unique owner -> store)
    #pragma unroll
    for (int it = 0; it < 2; ++it) {
        #pragma unroll
        for (int jt = 0; jt < 4; ++jt) {
            const int col = j0 + jt * 16 + c;
            const int g = m * N_SPK + col;
            const int istar = g / M_UTT;
            const int rloc = rb * 64 + wid * 32 + it * 16 + quad * 4;
            #pragma unroll
            for (int r = 0; r < 4; ++r) {
                if (rloc + r == istar) T[g] = acc[it][jt][r];
            }
        }
    }

    __syncthreads();
    if (t < 64) {   // merge the two row-halves, one store per column
        Psum[(size_t)bu * N_SPK + j0 + t] = red[0][t] + red[1][t];
    }
}

// ---------------------------------------------------------------------------
// Kernel 3: combine 16 row-block partials per (m,j) -> loss term; block sum;
// last-block writes output (ctr/accum zeroed by prep).
// term = (w*T+b) - ((w+b) + log S) = w*(T-1) - log S.
// ---------------------------------------------------------------------------
__global__ void combine_kernel(const float* __restrict__ Psum,
                               const float* __restrict__ T,
                               const float* __restrict__ wp,
                               int* __restrict__ ctr,
                               float* __restrict__ accum,
                               float* __restrict__ out) {
    const int p = blockIdx.x * 256 + threadIdx.x;
    const int m = p >> 10;
    const int j = p & 1023;
    const float w = wp[0];

    float S = 0.f;
    #pragma unroll
    for (int rb = 0; rb < 16; ++rb)
        S += Psum[(size_t)(m * 16 + rb) * N_SPK + j];
    const float term = w * (T[p] - 1.0f) - __logf(S);

    __shared__ float red[256];
    red[threadIdx.x] = term;
    __syncthreads();
    for (int o = 128; o > 0; o >>= 1) {
        if (threadIdx.x < o) red[threadIdx.x] += red[threadIdx.x + o];
        __syncthreads();
    }
    if (threadIdx.x == 0) {
        atomicAdd(accum, red[0]);
        __threadfence();
        const int old = atomicAdd(ctr, 1);
        if (old == 79) {
            const float a = atomicAdd(accum, 0.0f);   // coherent read
            out[0] = -a / (float)NM_ROWS;
        }
    }
}

// ---------------------------------------------------------------------------
extern "C" void kernel_launch(void* const* d_in, const int* in_sizes, int n_in,
                              void* d_out, int out_size, void* d_ws, size_t ws_size,
                              hipStream_t stream) {
    const float* emb = (const float*)d_in[0];
    const float* wp  = (const float*)d_in[1];
    float* out = (float*)d_out;

    char* ws = (char*)d_ws;
    //   Ehat bf16 [M][N][D] : 31,457,280  @ 0
    //   Chat bf16 [N][D]    :  1,572,864  @ 31,457,280
    //   Psum f32 [320][N]   :  1,310,720  @ 33,030,144
    //   T    f32 [M][N]     :     81,920  @ 34,340,864
    //   ctr  i32 + accum f32:          8  @ 34,422,784
    __hip_bfloat16* ehat = (__hip_bfloat16*)(ws);
    __hip_bfloat16* chat = (__hip_bfloat16*)(ws + 31457280);
    float* Psum  = (float*)(ws + 33030144);
    float* T     = (float*)(ws + 34340864);
    int*   ctr   = (int*)  (ws + 34422784);
    float* accum = (float*)(ws + 34422788);

    prep_kernel<<<dim3(N_SPK), dim3(384), 0, stream>>>(emb, ehat, chat, ctr, accum);
    gemm_fused_kernel<<<dim3(5120), dim3(128), 0, stream>>>(ehat, chat, wp, Psum, T);
    combine_kernel<<<dim3(80), dim3(256), 0, stream>>>(Psum, T, wp, ctr, accum, out);
}

// Round 14
// 138.111 us; speedup vs baseline: 1.5561x; 1.2364x over previous
//
#include <hip/hip_runtime.h>
#include <hip/hip_bf16.h>
#include <cstdint>

#define N_SPK 1024
#define M_UTT 20
#define D_DIM 768
#define NM_ROWS (N_SPK * M_UTT)   // 20480 utterances / rows

static constexpr float EPS = 1e-8f;

// s_waitcnt immediates (gfx9): vmcnt[3:0]=bits3:0, expcnt=6:4, lgkmcnt=11:8,
// vmcnt[5:4]=15:14.
#define WAIT_VM0   0x0F70   // vmcnt=0,  lgkm/exp don't-wait
#define WAIT_LGKM0 0xC07F   // lgkmcnt=0, vmcnt/exp don't-wait

typedef __attribute__((ext_vector_type(4))) float floatx4;  // MFMA accumulator

__device__ __forceinline__ void load16_to_lds(const void* g, void* l) {
    __builtin_amdgcn_global_load_lds(
        (const __attribute__((address_space(1))) uint32_t*)g,
        (__attribute__((address_space(3))) uint32_t*)l, 16, 0, 0);
}

__device__ __forceinline__ float wave_sum(float v) {
    #pragma unroll
    for (int o = 32; o > 0; o >>= 1) v += __shfl_xor(v, o);
    return v;
}

// pack two f32 -> two OCP e4m3 bytes (low word of result)
__device__ __forceinline__ unsigned short fp8pk(float a, float b) {
    return (unsigned short)(__builtin_amdgcn_cvt_pk_fp8_f32(a, b, 0, false) & 0xFFFF);
}

// ---------------------------------------------------------------------------
// Kernel 1 (prep): per speaker, read emb once (float2/thread, 384 thr),
// centroid + 20 utterance norms; write FP8 e4m3 Ehat ([m][i][d]) and Chat.
// Zero-inits ctr/accum.
// ---------------------------------------------------------------------------
__global__ __launch_bounds__(384) void prep_kernel(const float* __restrict__ emb,
                                                   unsigned char* __restrict__ ehat,
                                                   unsigned char* __restrict__ chat,
                                                   int* __restrict__ ctr,
                                                   float* __restrict__ accum) {
    const int i = blockIdx.x;      // speaker
    const int t = threadIdx.x;     // 0..383
    const int wave = t >> 6, lane = t & 63;

    if (i == 0 && t == 0) { *ctr = 0; *accum = 0.f; }

    const float2* src = (const float2*)(emb + (size_t)i * M_UTT * D_DIM);

    float2 v[M_UTT];
    float ss[M_UTT];
    float2 cen = {0.f, 0.f};
    #pragma unroll
    for (int m = 0; m < M_UTT; ++m) {
        const float2 x = src[m * 384 + t];
        v[m] = x;
        ss[m] = x.x * x.x + x.y * x.y;
        cen.x += x.x; cen.y += x.y;
    }
    cen.x *= (1.f / M_UTT); cen.y *= (1.f / M_UTT);
    float css = cen.x * cen.x + cen.y * cen.y;

    __shared__ float red[M_UTT + 1][6];
    #pragma unroll
    for (int m = 0; m < M_UTT; ++m) {
        const float s = wave_sum(ss[m]);
        if (lane == 0) red[m][wave] = s;
    }
    {
        const float s = wave_sum(css);
        if (lane == 0) red[M_UTT][wave] = s;
    }
    __syncthreads();

    #pragma unroll
    for (int m = 0; m < M_UTT; ++m) {
        const float tot = red[m][0] + red[m][1] + red[m][2] +
                          red[m][3] + red[m][4] + red[m][5];
        const float rn = 1.0f / fmaxf(sqrtf(tot), EPS);
        ((unsigned short*)(ehat + ((size_t)(m * N_SPK + i)) * D_DIM))[t] =
            fp8pk(v[m].x * rn, v[m].y * rn);
    }
    {
        const float tot = red[M_UTT][0] + red[M_UTT][1] + red[M_UTT][2] +
                          red[M_UTT][3] + red[M_UTT][4] + red[M_UTT][5];
        const float rn = 1.0f / fmaxf(sqrtf(tot), EPS);
        ((unsigned short*)(chat + (size_t)i * D_DIM))[t] =
            fp8pk(cen.x * rn, cen.y * rn);
    }
}

// ---------------------------------------------------------------------------
// Kernel 2: FP8 single-wave GEMM, BK=128 -> SIX K-iterations (vs 24 bf16).
// One wave per block, 64x64 tile, no __syncthreads (R8 skeleton, correctness-
// proven waitcnt discipline). Per iteration: stage 16 KB (A+B, 16 issues),
// vmcnt(0), then 4 k-sub-steps of {8 ds_read_b64 + 16 mfma_fp8} = 64 MFMA
// per drain (4x R7's compute density per stall). fp8 16x16x32 fragment:
// A[row=lane&15][k=quad*8+j] as 8 bytes (i64), analogous to bf16 layout.
// LDS 16 KB -> 10 blocks/CU. XCD swizzle + XOR chunk swizzle (2-way max).
// ---------------------------------------------------------------------------
__global__ __launch_bounds__(64) void gemm_fused_kernel(
        const unsigned char* __restrict__ ehat,
        const unsigned char* __restrict__ chat,
        const float* __restrict__ wp,
        float* __restrict__ Psum,
        float* __restrict__ T) {
    __shared__ unsigned char As[64 * 128];   // 8 KB (64 rows x 128 fp8)
    __shared__ unsigned char Bs[64 * 128];   // 8 KB

    const int lane = threadIdx.x;   // 0..63
    const int c = lane & 15;
    const int quad = lane >> 4;

    const int xcd = blockIdx.x & 7;
    const int idx = blockIdx.x >> 3;        // 0..639
    const int bu  = xcd * 40 + (idx >> 4);  // 0..319 (64-row tiles)
    const int bj  = idx & 15;               // 0..15  (bj fastest within XCD)
    const int m   = bu >> 4;                // 16 bu-tiles per m
    const int rb  = bu & 15;
    const int u0  = bu * 64;
    const int j0  = bj * 64;

    const unsigned char* Ag = ehat + (size_t)u0 * D_DIM;
    const unsigned char* Bg = chat + (size_t)j0 * D_DIM;

    // staging geometry: 512 16B chunks per operand; lane covers ci = s*64+lane
    // (HW lands lane's data at base+lane*16 == ci*16 — consistent by constr.)
    int goff[8];
    #pragma unroll
    for (int s = 0; s < 8; ++s) {
        const int ci  = s * 64 + lane;
        const int row = ci >> 3;
        const int q   = (ci & 7) ^ (row & 7);
        goff[s] = row * D_DIM + q * 16;
    }

    // fragment LDS byte offsets: for ks, frag row r: chunk q = ks*2+(quad>>1),
    // slot = r*8 + (q ^ (r&7)), + (quad&1)*8
    int slotA[4][4], slotB[4][4];   // [ks][it]
    #pragma unroll
    for (int ks = 0; ks < 4; ++ks) {
        const int q = ks * 2 + (quad >> 1);
        #pragma unroll
        for (int f = 0; f < 4; ++f) {
            const int r = f * 16 + c;
            slotA[ks][f] = (r * 8 + (q ^ (r & 7))) * 16 + (quad & 1) * 8;
            slotB[ks][f] = slotA[ks][f];
        }
    }

    floatx4 acc[4][4] = {};

    // prologue: stage K-tile 0
    #pragma unroll
    for (int s = 0; s < 8; ++s) {
        load16_to_lds(Ag + goff[s], As + (s * 64 + lane) * 16);
        load16_to_lds(Bg + goff[s], Bs + (s * 64 + lane) * 16);
    }

    for (int kt = 0; kt < 6; ++kt) {
        __builtin_amdgcn_s_waitcnt(WAIT_VM0);   // this tile's 16 loads landed

        #pragma unroll
        for (int ks = 0; ks < 4; ++ks) {
            long af[4], bf[4];
            #pragma unroll
            for (int it = 0; it < 4; ++it)
                af[it] = *(const long*)(As + slotA[ks][it]);
            #pragma unroll
            for (int jt = 0; jt < 4; ++jt)
                bf[jt] = *(const long*)(Bs + slotB[ks][jt]);

            #pragma unroll
            for (int it = 0; it < 4; ++it)
                #pragma unroll
                for (int jt = 0; jt < 4; ++jt)
                    acc[it][jt] = __builtin_amdgcn_mfma_f32_16x16x32_fp8_fp8(
                        af[it], bf[jt], acc[it][jt], 0, 0, 0);
        }

        if (kt < 5) {
            const int k0 = (kt + 1) * 128;
            __builtin_amdgcn_s_waitcnt(WAIT_LGKM0);   // ds_reads drained
            #pragma unroll
            for (int s = 0; s < 8; ++s) {
                load16_to_lds(Ag + goff[s] + k0, As + (s * 64 + lane) * 16);
                load16_to_lds(Bg + goff[s] + k0, Bs + (s * 64 + lane) * 16);
            }
        }
    }

    const float w = wp[0];

    // per-column fixed-offset partial: sum exp(w*(cos-1)) over the 64 rows
    #pragma unroll
    for (int jt = 0; jt < 4; ++jt) {
        float sm = 0.f;
        #pragma unroll
        for (int it = 0; it < 4; ++it)
            #pragma unroll
            for (int r = 0; r < 4; ++r)
                sm += __expf(w * (acc[it][jt][r] - 1.0f));
        sm += __shfl_xor(sm, 16);
        sm += __shfl_xor(sm, 32);
        if (quad == 0) Psum[(size_t)bu * N_SPK + j0 + jt * 16 + c] = sm;
    }

    // target sims: row within m-slab == (m*1024+col)/20 (unique owner -> store)
    #pragma unroll
    for (int it = 0; it < 4; ++it) {
        #pragma unroll
        for (int jt = 0; jt < 4; ++jt) {
            const int col = j0 + jt * 16 + c;
            const int g = m * N_SPK + col;
            const int istar = g / M_UTT;
            const int rloc = rb * 64 + it * 16 + quad * 4;
            #pragma unroll
            for (int r = 0; r < 4; ++r) {
                if (rloc + r == istar) T[g] = acc[it][jt][r];
            }
        }
    }
}

// ---------------------------------------------------------------------------
// Kernel 3: combine 16 row-block partials per (m,j) -> loss term; block sum;
// last-block writes output (ctr/accum zeroed by prep).
// term = (w*T+b) - ((w+b) + log S) = w*(T-1) - log S.
// ---------------------------------------------------------------------------
__global__ void combine_kernel(const float* __restrict__ Psum,
                               const float* __restrict__ T,
                               const float* __restrict__ wp,
                               int* __restrict__ ctr,
                               float* __restrict__ accum,
                               float* __restrict__ out) {
    const int p = blockIdx.x * 256 + threadIdx.x;
    const int m = p >> 10;
    const int j = p & 1023;
    const float w = wp[0];

    float S = 0.f;
    #pragma unroll
    for (int rb = 0; rb < 16; ++rb)
        S += Psum[(size_t)(m * 16 + rb) * N_SPK + j];
    const float term = w * (T[p] - 1.0f) - __logf(S);

    __shared__ float red[256];
    red[threadIdx.x] = term;
    __syncthreads();
    for (int o = 128; o > 0; o >>= 1) {
        if (threadIdx.x < o) red[threadIdx.x] += red[threadIdx.x + o];
        __syncthreads();
    }
    if (threadIdx.x == 0) {
        atomicAdd(accum, red[0]);
        __threadfence();
        const int old = atomicAdd(ctr, 1);
        if (old == 79) {
            const float a = atomicAdd(accum, 0.0f);   // coherent read
            out[0] = -a / (float)NM_ROWS;
        }
    }
}

// ---------------------------------------------------------------------------
extern "C" void kernel_launch(void* const* d_in, const int* in_sizes, int n_in,
                              void* d_out, int out_size, void* d_ws, size_t ws_size,
                              hipStream_t stream) {
    const float* emb = (const float*)d_in[0];
    const float* wp  = (const float*)d_in[1];
    float* out = (float*)d_out;

    char* ws = (char*)d_ws;
    //   Ehat fp8 [M][N][D] : 15,728,640  @ 0
    //   Chat fp8 [N][D]    :    786,432  @ 15,728,640
    //   Psum f32 [320][N]  :  1,310,720  @ 16,515,072
    //   T    f32 [M][N]    :     81,920  @ 17,825,792
    //   ctr i32 + accum f32:          8  @ 17,907,712
    unsigned char* ehat = (unsigned char*)(ws);
    unsigned char* chat = (unsigned char*)(ws + 15728640);
    float* Psum  = (float*)(ws + 16515072);
    float* T     = (float*)(ws + 17825792);
    int*   ctr   = (int*)  (ws + 17907712);
    float* accum = (float*)(ws + 17907716);

    prep_kernel<<<dim3(N_SPK), dim3(384), 0, stream>>>(emb, ehat, chat, ctr, accum);
    gemm_fused_kernel<<<dim3(5120), dim3(64), 0, stream>>>(ehat, chat, wp, Psum, T);
    combine_kernel<<<dim3(80), dim3(256), 0, stream>>>(Psum, T, wp, ctr, accum, out);
}